// Round 11
// baseline (278.541 us; speedup 1.0000x reference)
//
#include <hip/hip_runtime.h>
#include <hip/hip_bf16.h>

// Problem constants (from reference)
#define NN      50000
#define EE      800000
#define EP      (EE + NN)      // edges + self loops
#define F_IN    128
#define HID     64
#define HEADS   4
#define NCLS    40
#define SLOPE   0.2f

#define NB_SCAN ((NN + 1023) / 1024)   // 49 blocks of 1024 elements

typedef _Float16 half8v __attribute__((ext_vector_type(8)));
typedef _Float16 half4v __attribute__((ext_vector_type(4)));
typedef _Float16 half2v __attribute__((ext_vector_type(2)));
typedef float    f32x4  __attribute__((ext_vector_type(4)));
typedef unsigned int uint;

__device__ __forceinline__ float lrelu_exp(float e) {
    return __expf(fmaxf(e, SLOPE * e));   // max(e,0.2e) == leaky_relu for all e
}

// ---------------- CSR build ----------------

__global__ __launch_bounds__(256) void hist_kernel(const int* __restrict__ ei, int* deg) {
    int e = blockIdx.x * 256 + threadIdx.x;
    if (e < EE) atomicAdd(&deg[ei[EE + e]], 1);   // dst = ei[1][e]
}

// ---- multi-block exclusive scan over (deg+1) — the +1 is the self-loop ----
__global__ __launch_bounds__(256) void scan_blocks(const int* __restrict__ deg,
                                                   int* __restrict__ off,
                                                   int* __restrict__ bsum) {
    __shared__ int wsum[4];
    const int bid = blockIdx.x, t = threadIdx.x;
    const int base = bid * 1024 + t * 4;
    int d0 = 0, d1 = 0, d2 = 0, d3 = 0;
    if (base + 3 < NN) {
        int4 v = *(const int4*)(deg + base);
        d0 = v.x + 1; d1 = v.y + 1; d2 = v.z + 1; d3 = v.w + 1;
    } else {
        if (base + 0 < NN) d0 = deg[base + 0] + 1;
        if (base + 1 < NN) d1 = deg[base + 1] + 1;
        if (base + 2 < NN) d2 = deg[base + 2] + 1;
        if (base + 3 < NN) d3 = deg[base + 3] + 1;
    }
    const int tsum = d0 + d1 + d2 + d3;
    const int lane = t & 63, wv = t >> 6;
    int inc = tsum;
#pragma unroll
    for (int o = 1; o < 64; o <<= 1) {
        int u = __shfl_up(inc, o);
        if (lane >= o) inc += u;
    }
    if (lane == 63) wsum[wv] = inc;
    __syncthreads();
    int woff = 0;
#pragma unroll
    for (int w = 0; w < 4; ++w) woff += (w < wv) ? wsum[w] : 0;
    const int excl = woff + inc - tsum;
    if (base + 3 < NN) {
        int4 o4;
        o4.x = excl;
        o4.y = excl + d0;
        o4.z = excl + d0 + d1;
        o4.w = excl + d0 + d1 + d2;
        *(int4*)(off + base) = o4;
    } else {
        if (base + 0 < NN) off[base + 0] = excl;
        if (base + 1 < NN) off[base + 1] = excl + d0;
        if (base + 2 < NN) off[base + 2] = excl + d0 + d1;
        if (base + 3 < NN) off[base + 3] = excl + d0 + d1 + d2;
    }
    if (t == 255) bsum[bid] = woff + inc;   // block total
}

__global__ __launch_bounds__(64) void scan_spine(int* __restrict__ bsum,
                                                 int* __restrict__ off) {
    const int lane = threadIdx.x;
    int v = (lane < NB_SCAN) ? bsum[lane] : 0;
    int inc = v;
#pragma unroll
    for (int o = 1; o < 64; o <<= 1) {
        int u = __shfl_up(inc, o);
        if (lane >= o) inc += u;
    }
    if (lane < NB_SCAN) bsum[lane] = inc - v;   // exclusive prefix
    if (lane == 63) off[NN] = inc;              // grand total == EP
}

__global__ __launch_bounds__(256) void scan_apply(const int* __restrict__ bsum,
                                                  int* __restrict__ off,
                                                  int* __restrict__ cur) {
    const int bid = blockIdx.x, t = threadIdx.x;
    const int boff = bsum[bid];
    const int base = bid * 1024 + t * 4;
    if (base + 3 < NN) {
        int4 v = *(const int4*)(off + base);
        v.x += boff; v.y += boff; v.z += boff; v.w += boff;
        *(int4*)(off + base) = v;
        *(int4*)(cur + base) = v;
    } else {
        for (int i = 0; i < 4; ++i)
            if (base + i < NN) {
                int v = off[base + i] + boff;
                off[base + i] = v;
                cur[base + i] = v;
            }
    }
}

__global__ __launch_bounds__(256) void scatter_kernel(const int* __restrict__ ei,
                                                      int* __restrict__ cur,
                                                      int* __restrict__ csr) {
    int i = blockIdx.x * 256 + threadIdx.x;
    if (i >= EP) return;
    int s, d;
    if (i < NN) { s = i; d = i; }           // self loop
    else { int e = i - NN; s = ei[e]; d = ei[EE + e]; }
    int pos = atomicAdd(&cur[d], 1);
    csr[pos] = s;
}

// ---------------- W1 -> fragment-packed fp16 table (once per launch) ----------------
// sigma(g,j) = 8g+j applied identically to A and B fragments (K-perm invariance).
__global__ __launch_bounds__(256) void prep_w1(const float* __restrict__ W1,
                                               _Float16* __restrict__ W1p) {
    int idx = blockIdx.x * 256 + threadIdx.x;   // 16*4*64 = 4096 fragments-of-8
    if (idx >= 16 * 4 * 64) return;
    int l = idx & 63, kk = (idx >> 6) & 3, f = idx >> 8;
    int k0 = 32 * kk + 8 * (l >> 4);
    int c  = 16 * f + (l & 15);
    half8v v;
#pragma unroll
    for (int j = 0; j < 8; ++j) v[j] = (_Float16)W1[(size_t)(k0 + j) * 256 + c];
    *(half8v*)(W1p + (size_t)idx * 8) = v;
}

// ---- layer-1 folded alpha: vs1[h][k] = sum_c W1[k][64h+c]*a_src1[h][c]; pack as
// one extra MFMA B-block (cols 0..3 = as1 heads, 4..7 = ad1 heads, 8..15 = 0).
__global__ __launch_bounds__(256) void prep_v1(const float* __restrict__ W1,
                                               const float* __restrict__ a_src1,
                                               const float* __restrict__ a_dst1,
                                               _Float16* __restrict__ W1e) {
    __shared__ float V[8][128];
    const int t = threadIdx.x;
#pragma unroll
    for (int rep = 0; rep < 4; ++rep) {
        int idx = rep * 256 + t;        // 0..1023
        int jrow = idx >> 7;            // 0..7: h=jrow&3, src(0-3)/dst(4-7)
        int k = idx & 127;
        int h = jrow & 3;
        const float* av = (jrow < 4) ? a_src1 : a_dst1;
        float s = 0.f;
        for (int c = 0; c < 64; ++c)
            s = fmaf(W1[(size_t)k * 256 + h * 64 + c], av[h * 64 + c], s);
        V[jrow][k] = s;
    }
    __syncthreads();
    // pack: t -> (kk = t>>6, l = t&63)
    int kk = t >> 6, l = t & 63;
    int c = l & 15;
    half8v v;
#pragma unroll
    for (int j = 0; j < 8; ++j) {
        int k = 32 * kk + 8 * (l >> 4) + j;
        float x = (c < 8) ? V[c][k] : 0.f;
        v[j] = (_Float16)x;
    }
    *(half8v*)(W1e + (size_t)t * 8) = v;
}

// ---- layer-2 folded logit vectors: vs[h][k] = sum_c W2[k, h*40+c] * a_src2[h][c] ----
__global__ __launch_bounds__(256) void prep_v(const float* __restrict__ W2,
                                              const float* __restrict__ a_src2,
                                              const float* __restrict__ a_dst2,
                                              float* __restrict__ vs,
                                              float* __restrict__ vd) {
    int idx = threadIdx.x;              // 4 heads x 64 k
    int h = idx >> 6, k = idx & 63;
    float s = 0.f, d = 0.f;
    for (int c = 0; c < NCLS; ++c) {
        float w = W2[(size_t)k * 160 + h * 40 + c];
        s = fmaf(w, a_src2[h * 40 + c], s);
        d = fmaf(w, a_dst2[h * 40 + c], d);
    }
    vs[idx] = s; vd[idx] = d;
}

// ---- W2 -> fragment-packed fp16 for gemm_out: B[kappa][c], kappa=(h*64+kx), 48 cols pad ----
__global__ __launch_bounds__(256) void prep_w2(const float* __restrict__ W2,
                                               _Float16* __restrict__ Bp) {
    int idx = blockIdx.x * 256 + threadIdx.x;   // 3*8*64 = 1536 fragments-of-8
    if (idx >= 1536) return;
    int l = idx & 63, kk = (idx >> 6) & 7, n = idx >> 9;
    int c = 16 * n + (l & 15);
    half8v v;
#pragma unroll
    for (int j = 0; j < 8; ++j) {
        int kap = 32 * kk + 8 * (l >> 4) + j;   // kappa in [0,256)
        float w = (c < NCLS) ? W2[(size_t)(kap & 63) * 160 + (kap >> 6) * 40 + c] : 0.f;
        v[j] = (_Float16)w;
    }
    *(half8v*)(Bp + (size_t)idx * 8) = v;
}

// ---------------- layer-1 GEMM via f16 MFMA + fused alpha columns ----------------
__global__ __launch_bounds__(256)
void gemm1_mfma(const float* __restrict__ A, const _Float16* __restrict__ W1p,
                const _Float16* __restrict__ W1e, _Float16* __restrict__ h1h,
                float* __restrict__ as1, float* __restrict__ ad1, int M) {
    __shared__ _Float16 Al[128 * 128];   // 32 KB
    const int t    = threadIdx.x;
    const int row0 = blockIdx.x * 128;

#pragma unroll
    for (int i = 0; i < 16; ++i) {
        int flat = i * 1024 + t * 4;
        int r = flat >> 7, c = flat & 127;
        int rg = row0 + r; if (rg >= M) rg = M - 1;
        float4 v = *(const float4*)(A + (size_t)rg * 128 + c);
        half4v hv;
        hv.x = (_Float16)v.x; hv.y = (_Float16)v.y;
        hv.z = (_Float16)v.z; hv.w = (_Float16)v.w;
        int byte = (r * 256 + c * 2) ^ ((r & 7) << 4);
        *(half4v*)((char*)Al + byte) = hv;
    }
    __syncthreads();

    const int lane = t & 63;
    const int w    = t >> 6;
    const int g    = lane >> 4, cc = lane & 15;

    half8v a[2][4];
#pragma unroll
    for (int m = 0; m < 2; ++m)
#pragma unroll
        for (int kk = 0; kk < 4; ++kk) {
            int r = 32 * w + 16 * m + cc;
            int byte = (r * 256 + (32 * kk + 8 * g) * 2) ^ ((r & 7) << 4);
            a[m][kk] = *(const half8v*)((const char*)Al + byte);
        }

    f32x4 acc[16][2];
#pragma unroll
    for (int n = 0; n < 16; ++n)
#pragma unroll
        for (int m = 0; m < 2; ++m)
#pragma unroll
            for (int i = 0; i < 4; ++i) acc[n][m][i] = 0.f;

#pragma unroll
    for (int n = 0; n < 16; ++n) {
        half8v b[4];
#pragma unroll
        for (int kk = 0; kk < 4; ++kk)
            b[kk] = *(const half8v*)(W1p + ((size_t)(n * 4 + kk) * 64 + lane) * 8);
#pragma unroll
        for (int kk = 0; kk < 4; ++kk) {
            acc[n][0] = __builtin_amdgcn_mfma_f32_16x16x32_f16(a[0][kk], b[kk], acc[n][0], 0, 0, 0);
            acc[n][1] = __builtin_amdgcn_mfma_f32_16x16x32_f16(a[1][kk], b[kk], acc[n][1], 0, 0, 0);
        }
    }
    // extra alpha block (cols: 0..3 as1, 4..7 ad1)
    f32x4 acc16[2];
#pragma unroll
    for (int m = 0; m < 2; ++m)
#pragma unroll
        for (int i = 0; i < 4; ++i) acc16[m][i] = 0.f;
    {
        half8v be[4];
#pragma unroll
        for (int kk = 0; kk < 4; ++kk)
            be[kk] = *(const half8v*)(W1e + ((size_t)(kk * 64 + lane)) * 8);
#pragma unroll
        for (int kk = 0; kk < 4; ++kk) {
            acc16[0] = __builtin_amdgcn_mfma_f32_16x16x32_f16(a[0][kk], be[kk], acc16[0], 0, 0, 0);
            acc16[1] = __builtin_amdgcn_mfma_f32_16x16x32_f16(a[1][kk], be[kk], acc16[1], 0, 0, 0);
        }
    }

#pragma unroll
    for (int m = 0; m < 2; ++m)
#pragma unroll
        for (int i = 0; i < 4; ++i) {
            int r = row0 + 32 * w + 16 * m + 4 * g + i;
            bool ok = (r < M) && !(cc & 1);
#pragma unroll
            for (int n = 0; n < 16; ++n) {
                float v0 = acc[n][m][i];
                float v1 = __shfl_xor(v0, 1);
                if (ok) {
                    half2v h2; h2.x = (_Float16)v0; h2.y = (_Float16)v1;
                    *(half2v*)(h1h + (size_t)r * 256 + n * 16 + cc) = h2;
                }
            }
            if (r < M) {
                float v = acc16[m][i];
                if (cc < 4)      as1[r * 4 + cc]     = v;
                else if (cc < 8) ad1[r * 4 + cc - 4] = v;
            }
        }
}

// ---------------- layer-1 edge softmax + aggregation ----------------
// x8 edge unroll; weights computed once per (edge,head) by lanes 0..31 and
// shuffled to consumers; 32-bit byte-offset addressing.

__global__ __launch_bounds__(256)
void agg1_kernel(const _Float16* __restrict__ h1h, const float* __restrict__ as1,
                 const float* __restrict__ ad1, const int* __restrict__ off,
                 const int* __restrict__ csr, const float* __restrict__ b1,
                 const float* __restrict__ vs, const float* __restrict__ vd,
                 _Float16* __restrict__ h1of, float* __restrict__ as2,
                 float* __restrict__ ad2) {
    int n = (blockIdx.x * 256 + threadIdx.x) >> 6;
    if (n >= NN) return;
    const int lane = threadIdx.x & 63;
    const int hd = lane >> 4, q = lane & 15;
    const int eSel = lane & 7;            // weight-compute role: edge
    const int hW   = (lane >> 3) & 3;     //                      head
    const float advW = ad1[n * 4 + hW];
    const float adv  = ad1[n * 4 + hd];
    const int srcB = hd << 3;
    const uint laneB = (uint)lane * 8u;
    const char* hb  = (const char*)h1h;
    const char* asb = (const char*)as1;
    const uint hW4 = (uint)hW * 4u;
    int e0 = off[n], e1 = off[n + 1];
    float a0 = 0.f, a1 = 0.f, a2 = 0.f, a3 = 0.f, den = 0.f;
    int j = e0;
    for (; j + 8 <= e1; j += 8) {
        int se = csr[j + eSel];
        float er = *(const float*)(asb + (((uint)se << 4) + hW4)) + advW;
        float wA = lrelu_exp(er);
        int s0 = csr[j], s1 = csr[j + 1], s2 = csr[j + 2], s3 = csr[j + 3];
        int s4 = csr[j + 4], s5 = csr[j + 5], s6 = csr[j + 6], s7 = csr[j + 7];
        half4v v0 = *(const half4v*)(hb + (((uint)s0 << 9) + laneB));
        half4v v1 = *(const half4v*)(hb + (((uint)s1 << 9) + laneB));
        half4v v2 = *(const half4v*)(hb + (((uint)s2 << 9) + laneB));
        half4v v3 = *(const half4v*)(hb + (((uint)s3 << 9) + laneB));
        half4v v4 = *(const half4v*)(hb + (((uint)s4 << 9) + laneB));
        half4v v5 = *(const half4v*)(hb + (((uint)s5 << 9) + laneB));
        half4v v6 = *(const half4v*)(hb + (((uint)s6 << 9) + laneB));
        half4v v7 = *(const half4v*)(hb + (((uint)s7 << 9) + laneB));
        float w0 = __shfl(wA, srcB + 0), w1 = __shfl(wA, srcB + 1);
        float w2 = __shfl(wA, srcB + 2), w3 = __shfl(wA, srcB + 3);
        float w4 = __shfl(wA, srcB + 4), w5 = __shfl(wA, srcB + 5);
        float w6 = __shfl(wA, srcB + 6), w7 = __shfl(wA, srcB + 7);
        den += ((w0 + w1) + (w2 + w3)) + ((w4 + w5) + (w6 + w7));
        a0 = fmaf(w0, (float)v0.x, a0); a1 = fmaf(w0, (float)v0.y, a1);
        a2 = fmaf(w0, (float)v0.z, a2); a3 = fmaf(w0, (float)v0.w, a3);
        a0 = fmaf(w1, (float)v1.x, a0); a1 = fmaf(w1, (float)v1.y, a1);
        a2 = fmaf(w1, (float)v1.z, a2); a3 = fmaf(w1, (float)v1.w, a3);
        a0 = fmaf(w2, (float)v2.x, a0); a1 = fmaf(w2, (float)v2.y, a1);
        a2 = fmaf(w2, (float)v2.z, a2); a3 = fmaf(w2, (float)v2.w, a3);
        a0 = fmaf(w3, (float)v3.x, a0); a1 = fmaf(w3, (float)v3.y, a1);
        a2 = fmaf(w3, (float)v3.z, a2); a3 = fmaf(w3, (float)v3.w, a3);
        a0 = fmaf(w4, (float)v4.x, a0); a1 = fmaf(w4, (float)v4.y, a1);
        a2 = fmaf(w4, (float)v4.z, a2); a3 = fmaf(w4, (float)v4.w, a3);
        a0 = fmaf(w5, (float)v5.x, a0); a1 = fmaf(w5, (float)v5.y, a1);
        a2 = fmaf(w5, (float)v5.z, a2); a3 = fmaf(w5, (float)v5.w, a3);
        a0 = fmaf(w6, (float)v6.x, a0); a1 = fmaf(w6, (float)v6.y, a1);
        a2 = fmaf(w6, (float)v6.z, a2); a3 = fmaf(w6, (float)v6.w, a3);
        a0 = fmaf(w7, (float)v7.x, a0); a1 = fmaf(w7, (float)v7.y, a1);
        a2 = fmaf(w7, (float)v7.z, a2); a3 = fmaf(w7, (float)v7.w, a3);
    }
    for (; j < e1; ++j) {
        int s = csr[j];
        float w = lrelu_exp(as1[s * 4 + hd] + adv);
        den += w;
        half4v hv = *(const half4v*)(hb + (((uint)s << 9) + laneB));
        a0 = fmaf(w, (float)hv.x, a0); a1 = fmaf(w, (float)hv.y, a1);
        a2 = fmaf(w, (float)hv.z, a2); a3 = fmaf(w, (float)hv.w, a3);
    }
    float inv = 1.f / (den + 1e-16f);
    a0 *= inv; a1 *= inv; a2 *= inv; a3 *= inv;
    a0 += __shfl_xor(a0, 16); a0 += __shfl_xor(a0, 32);
    a1 += __shfl_xor(a1, 16); a1 += __shfl_xor(a1, 32);
    a2 += __shfl_xor(a2, 16); a2 += __shfl_xor(a2, 32);
    a3 += __shfl_xor(a3, 16); a3 += __shfl_xor(a3, 32);
    if (hd == 0) {
        int c = q * 4;
        float o0 = fmaxf(a0 * 0.25f + b1[c + 0], 0.f);
        float o1 = fmaxf(a1 * 0.25f + b1[c + 1], 0.f);
        float o2 = fmaxf(a2 * 0.25f + b1[c + 2], 0.f);
        float o3 = fmaxf(a3 * 0.25f + b1[c + 3], 0.f);
        half4v hv;
        hv.x = (_Float16)o0; hv.y = (_Float16)o1;
        hv.z = (_Float16)o2; hv.w = (_Float16)o3;
        *(half4v*)(h1of + (size_t)n * 64 + c) = hv;
        // fused layer-2 logits: as2[n,h] = sum_k h1o[n,k] * vs[h][k]  (exact f32)
#pragma unroll
        for (int h = 0; h < 4; ++h) {
            float4 cs = *(const float4*)(vs + h * 64 + c);
            float4 cd = *(const float4*)(vd + h * 64 + c);
            float s = o0 * cs.x + o1 * cs.y + o2 * cs.z + o3 * cs.w;
            float d = o0 * cd.x + o1 * cd.y + o2 * cd.z + o3 * cd.w;
#pragma unroll
            for (int m = 1; m <= 8; m <<= 1) {
                s += __shfl_xor(s, m);
                d += __shfl_xor(d, m);
            }
            if (q == 0) { as2[n * 4 + h] = s; ad2[n * 4 + h] = d; }
        }
    }
}

// ---------------- layer-2 aggregation: gather RAW h1o (fp16), per-head accum ----------------

__global__ __launch_bounds__(256)
void agg2_kernel(const _Float16* __restrict__ h1of, const float* __restrict__ as2,
                 const float* __restrict__ ad2, const int* __restrict__ off,
                 const int* __restrict__ csr, _Float16* __restrict__ g2h) {
    int n = (blockIdx.x * 256 + threadIdx.x) >> 6;
    if (n >= NN) return;
    const int lane = threadIdx.x & 63;
    const int hd = lane >> 4, q = lane & 15;
    const int eSel = lane & 7;
    const int hW   = (lane >> 3) & 3;
    const float advW = ad2[n * 4 + hW];
    const float adv  = ad2[n * 4 + hd];
    const int srcB = hd << 3;
    const uint qB = (uint)q * 8u;
    const char* hb  = (const char*)h1of;
    const char* asb = (const char*)as2;
    const uint hW4 = (uint)hW * 4u;
    int e0 = off[n], e1 = off[n + 1];
    float a0 = 0.f, a1 = 0.f, a2 = 0.f, a3 = 0.f, den = 0.f;
    int j = e0;
    for (; j + 8 <= e1; j += 8) {
        int se = csr[j + eSel];
        float er = *(const float*)(asb + (((uint)se << 4) + hW4)) + advW;
        float wA = lrelu_exp(er);
        int s0 = csr[j], s1 = csr[j + 1], s2 = csr[j + 2], s3 = csr[j + 3];
        int s4 = csr[j + 4], s5 = csr[j + 5], s6 = csr[j + 6], s7 = csr[j + 7];
        half4v v0 = *(const half4v*)(hb + (((uint)s0 << 7) + qB));
        half4v v1 = *(const half4v*)(hb + (((uint)s1 << 7) + qB));
        half4v v2 = *(const half4v*)(hb + (((uint)s2 << 7) + qB));
        half4v v3 = *(const half4v*)(hb + (((uint)s3 << 7) + qB));
        half4v v4 = *(const half4v*)(hb + (((uint)s4 << 7) + qB));
        half4v v5 = *(const half4v*)(hb + (((uint)s5 << 7) + qB));
        half4v v6 = *(const half4v*)(hb + (((uint)s6 << 7) + qB));
        half4v v7 = *(const half4v*)(hb + (((uint)s7 << 7) + qB));
        float w0 = __shfl(wA, srcB + 0), w1 = __shfl(wA, srcB + 1);
        float w2 = __shfl(wA, srcB + 2), w3 = __shfl(wA, srcB + 3);
        float w4 = __shfl(wA, srcB + 4), w5 = __shfl(wA, srcB + 5);
        float w6 = __shfl(wA, srcB + 6), w7 = __shfl(wA, srcB + 7);
        den += ((w0 + w1) + (w2 + w3)) + ((w4 + w5) + (w6 + w7));
        a0 = fmaf(w0, (float)v0.x, a0); a1 = fmaf(w0, (float)v0.y, a1);
        a2 = fmaf(w0, (float)v0.z, a2); a3 = fmaf(w0, (float)v0.w, a3);
        a0 = fmaf(w1, (float)v1.x, a0); a1 = fmaf(w1, (float)v1.y, a1);
        a2 = fmaf(w1, (float)v1.z, a2); a3 = fmaf(w1, (float)v1.w, a3);
        a0 = fmaf(w2, (float)v2.x, a0); a1 = fmaf(w2, (float)v2.y, a1);
        a2 = fmaf(w2, (float)v2.z, a2); a3 = fmaf(w2, (float)v2.w, a3);
        a0 = fmaf(w3, (float)v3.x, a0); a1 = fmaf(w3, (float)v3.y, a1);
        a2 = fmaf(w3, (float)v3.z, a2); a3 = fmaf(w3, (float)v3.w, a3);
        a0 = fmaf(w4, (float)v4.x, a0); a1 = fmaf(w4, (float)v4.y, a1);
        a2 = fmaf(w4, (float)v4.z, a2); a3 = fmaf(w4, (float)v4.w, a3);
        a0 = fmaf(w5, (float)v5.x, a0); a1 = fmaf(w5, (float)v5.y, a1);
        a2 = fmaf(w5, (float)v5.z, a2); a3 = fmaf(w5, (float)v5.w, a3);
        a0 = fmaf(w6, (float)v6.x, a0); a1 = fmaf(w6, (float)v6.y, a1);
        a2 = fmaf(w6, (float)v6.z, a2); a3 = fmaf(w6, (float)v6.w, a3);
        a0 = fmaf(w7, (float)v7.x, a0); a1 = fmaf(w7, (float)v7.y, a1);
        a2 = fmaf(w7, (float)v7.z, a2); a3 = fmaf(w7, (float)v7.w, a3);
    }
    for (; j < e1; ++j) {
        int s = csr[j];
        float w = lrelu_exp(as2[s * 4 + hd] + adv);
        den += w;
        half4v hv = *(const half4v*)(hb + (((uint)s << 7) + qB));
        a0 = fmaf(w, (float)hv.x, a0); a1 = fmaf(w, (float)hv.y, a1);
        a2 = fmaf(w, (float)hv.z, a2); a3 = fmaf(w, (float)hv.w, a3);
    }
    float inv = 1.f / (den + 1e-16f);
    half4v g;
    g.x = (_Float16)(a0 * inv); g.y = (_Float16)(a1 * inv);
    g.z = (_Float16)(a2 * inv); g.w = (_Float16)(a3 * inv);
    *(half4v*)(g2h + (size_t)n * 256 + hd * 64 + q * 4) = g;   // kappa = hd*64 + k
}

// ---------------- output GEMM via f16 MFMA: out[N,40] = 0.25 * g2[N,256] @ B + b2 ----------------

__global__ __launch_bounds__(256)
void gemm_out(const _Float16* __restrict__ g2h, const _Float16* __restrict__ Bp,
              const float* __restrict__ b2, float* __restrict__ out, int M) {
    __shared__ _Float16 Al[128 * 256];   // 64 KB
    const int t    = threadIdx.x;
    const int row0 = blockIdx.x * 128;

#pragma unroll
    for (int i = 0; i < 16; ++i) {
        int chunk = i * 256 + t;          // 4096 chunks of 8 halfs
        int r = chunk >> 5, c = (chunk & 31) * 8;
        int rg = row0 + r; if (rg >= M) rg = M - 1;
        half8v v = *(const half8v*)(g2h + (size_t)rg * 256 + c);
        int byte = (r * 512 + c * 2) ^ ((r & 7) << 4);
        *(half8v*)((char*)Al + byte) = v;
    }
    __syncthreads();

    const int lane = t & 63, w = t >> 6;
    const int g = lane >> 4, cc = lane & 15;

    half8v a[2][8];
#pragma unroll
    for (int m = 0; m < 2; ++m)
#pragma unroll
        for (int kk = 0; kk < 8; ++kk) {
            int r = 32 * w + 16 * m + cc;
            int byte = (r * 512 + (32 * kk + 8 * g) * 2) ^ ((r & 7) << 4);
            a[m][kk] = *(const half8v*)((const char*)Al + byte);
        }

    f32x4 acc[2][3];
#pragma unroll
    for (int m = 0; m < 2; ++m)
#pragma unroll
        for (int n = 0; n < 3; ++n)
#pragma unroll
            for (int i = 0; i < 4; ++i) acc[m][n][i] = 0.f;

#pragma unroll
    for (int n = 0; n < 3; ++n)
#pragma unroll
        for (int kk = 0; kk < 8; ++kk) {
            half8v b = *(const half8v*)(Bp + ((size_t)(n * 8 + kk) * 64 + lane) * 8);
            acc[0][n] = __builtin_amdgcn_mfma_f32_16x16x32_f16(a[0][kk], b, acc[0][n], 0, 0, 0);
            acc[1][n] = __builtin_amdgcn_mfma_f32_16x16x32_f16(a[1][kk], b, acc[1][n], 0, 0, 0);
        }

#pragma unroll
    for (int m = 0; m < 2; ++m)
#pragma unroll
        for (int i = 0; i < 4; ++i) {
            int r = row0 + 32 * w + 16 * m + 4 * g + i;
            if (r < M) {
#pragma unroll
                for (int n = 0; n < 3; ++n) {
                    int c = 16 * n + cc;
                    if (c < NCLS)
                        out[(size_t)r * 40 + c] = 0.25f * acc[m][n][i] + b2[c];
                }
            }
        }
}

// ---------------- launch ----------------

extern "C" void kernel_launch(void* const* d_in, const int* in_sizes, int n_in,
                              void* d_out, int out_size, void* d_ws, size_t ws_size,
                              hipStream_t stream) {
    const float* x      = (const float*)d_in[0];
    const int*   ei     = (const int*)  d_in[1];   // [2][E], int32 per harness
    const float* W1     = (const float*)d_in[2];
    const float* a_src1 = (const float*)d_in[3];
    const float* a_dst1 = (const float*)d_in[4];
    const float* b1     = (const float*)d_in[5];
    const float* W2     = (const float*)d_in[6];
    const float* a_src2 = (const float*)d_in[7];
    const float* a_dst2 = (const float*)d_in[8];
    const float* b2     = (const float*)d_in[9];
    float* out = (float*)d_out;

    char* p = (char*)d_ws;
    auto alloc = [&](size_t bytes) {
        void* r = (void*)p;
        p += (bytes + 255) & ~(size_t)255;
        return r;
    };
    int*       deg  = (int*)alloc((size_t)NN * 4);
    int*       off  = (int*)alloc((size_t)(NN + 1) * 4);
    int*       cur  = (int*)alloc((size_t)NN * 4);
    int*       bsum = (int*)alloc((size_t)NB_SCAN * 4);
    int*       csr  = (int*)alloc((size_t)EP * 4);
    _Float16*  W1p  = (_Float16*)alloc((size_t)128 * 256 * 2);  // fragment-packed W1
    _Float16*  W1e  = (_Float16*)alloc((size_t)256 * 8 * 2);    // fragment-packed alpha1 cols
    _Float16*  Bp   = (_Float16*)alloc((size_t)1536 * 8 * 2);   // fragment-packed W2 (48 cols)
    float*     vs   = (float*)alloc((size_t)256 * 4);           // folded a_src2 (per head, 64-d)
    float*     vd   = (float*)alloc((size_t)256 * 4);
    _Float16*  h1h  = (_Float16*)alloc((size_t)NN * 256 * 2);   // fp16 gather table L1
    float*     as1  = (float*)alloc((size_t)NN * 4 * 4);
    float*     ad1  = (float*)alloc((size_t)NN * 4 * 4);
    _Float16*  h1of = (_Float16*)alloc((size_t)NN * 64 * 2);    // fp16 h1o gather table (6.4 MB)
    float*     as2  = (float*)alloc((size_t)NN * 4 * 4);
    float*     ad2  = (float*)alloc((size_t)NN * 4 * 4);
    _Float16*  g2h  = (_Float16*)alloc((size_t)NN * 256 * 2);   // aggregated per-head h1o

    // CSR over dst (shared by both layers); deg=0 + implicit self-loop in scan
    hipMemsetAsync(deg, 0, (size_t)NN * 4, stream);
    hist_kernel<<<(EE + 255) / 256, 256, 0, stream>>>(ei, deg);
    scan_blocks<<<NB_SCAN, 256, 0, stream>>>(deg, off, bsum);
    scan_spine<<<1, 64, 0, stream>>>(bsum, off);
    scan_apply<<<NB_SCAN, 256, 0, stream>>>(bsum, off, cur);
    scatter_kernel<<<(EP + 255) / 256, 256, 0, stream>>>(ei, cur, csr);

    // weight prep (independent of CSR)
    prep_w1<<<16, 256, 0, stream>>>(W1, W1p);
    prep_v1<<<1, 256, 0, stream>>>(W1, a_src1, a_dst1, W1e);
    prep_v<<<1, 256, 0, stream>>>(W2, a_src2, a_dst2, vs, vd);
    prep_w2<<<6, 256, 0, stream>>>(W2, Bp);

    // layer 1 (alpha fused into GEMM as extra MFMA columns)
    gemm1_mfma<<<(NN + 127) / 128, 256, 0, stream>>>(x, W1p, W1e, h1h, as1, ad1, NN);
    agg1_kernel<<<(NN + 3) / 4, 256, 0, stream>>>(h1h, as1, ad1, off, csr, b1,
                                                  vs, vd, h1of, as2, ad2);

    // layer 2 (aggregate raw h1o per head, then one MFMA transform)
    agg2_kernel<<<(NN + 3) / 4, 256, 0, stream>>>(h1of, as2, ad2, off, csr, g2h);
    gemm_out<<<(NN + 127) / 128, 256, 0, stream>>>(g2h, Bp, b2, out, NN);
}